// Round 1
// baseline (3906.277 us; speedup 1.0000x reference)
//
#include <hip/hip_runtime.h>
#include <math.h>

// Problem dims (fixed by reference setup_inputs)
constexpr int NB = 32;      // batch
constexpr int NT = 1024;    // time
constexpr int BT = 32768;   // NB*NT rows
constexpr int DD = 512;     // model dim
constexpr int KC = 128;     // k channels (2x2 matrices)
constexpr int NL = 6;       // layers
constexpr int NV = 2048;    // vocab
constexpr int HH = 256;     // k*2
constexpr int FF = 512;     // k*4
constexpr int NC = NV / 64; // vocab chunks for loss stage1 = 32
constexpr float EPS = 1.1920929e-07f;
constexpr float SOFTCAP = 30.0f;

__device__ __forceinline__ float wave_reduce_sum(float v) {
#pragma unroll
    for (int m = 32; m >= 1; m >>= 1) v += __shfl_xor(v, m, 64);
    return v;
}
__device__ __forceinline__ float wave_reduce_max(float v) {
#pragma unroll
    for (int m = 32; m >= 1; m >>= 1) v = fmaxf(v, __shfl_xor(v, m, 64));
    return v;
}

// x[row] = rmsnorm(tok_emb[ids[row]])   (block = 256 threads, one row)
__global__ __launch_bounds__(256) void embed_rms_kernel(
        const int* __restrict__ ids, const float* __restrict__ emb,
        float* __restrict__ x) {
    __shared__ float sw[4];
    int row = blockIdx.x;
    int id = ids[row];
    const float* e = emb + (size_t)id * DD;
    float* xo = x + (size_t)row * DD;
    int t = threadIdx.x;
    float v0 = e[t], v1 = e[t + 256];
    float ss = wave_reduce_sum(v0 * v0 + v1 * v1);
    if ((t & 63) == 0) sw[t >> 6] = ss;
    __syncthreads();
    ss = sw[0] + sw[1] + sw[2] + sw[3];
    float sc = rsqrtf(ss * (1.0f / DD) + EPS);
    xo[t] = v0 * sc;
    xo[t + 256] = v1 * sc;
}

// irms[row] = rsqrt(mean(x[row]^2) + EPS)
__global__ __launch_bounds__(256) void rowrms_kernel(
        const float* __restrict__ x, float* __restrict__ irms) {
    __shared__ float sw[4];
    int row = blockIdx.x;
    const float* xr = x + (size_t)row * DD;
    int t = threadIdx.x;
    float v0 = xr[t], v1 = xr[t + 256];
    float ss = wave_reduce_sum(v0 * v0 + v1 * v1);
    if ((t & 63) == 0) sw[t >> 6] = ss;
    __syncthreads();
    ss = sw[0] + sw[1] + sw[2] + sw[3];
    if (t == 0) irms[row] = rsqrtf(ss * (1.0f / DD) + EPS);
}

// C[m,n] = sum_k A[m,k]*B[n,k]   (B row-major N x K)
// MODE 0: C = result, A scaled per-row by rowScale (if non-null)
// MODE 1: C[m,n] += dscale[n]*result   (residual into x)
// 64x64 tile, 256 threads, 4x4 micro-tile, K-step 16.
template <int MODE>
__global__ __launch_bounds__(256) void gemm_bt_kernel(
        const float* __restrict__ A, const float* __restrict__ Bw,
        float* __restrict__ C, int N, int Kd,
        const float* __restrict__ rowScale, const float* __restrict__ dscale) {
    __shared__ float As[16][68];
    __shared__ float Bs[16][68];
    int n0 = blockIdx.x * 64;
    int m0 = blockIdx.y * 64;
    int tid = threadIdx.x;
    int tx = tid & 15, ty = tid >> 4;
    int lrow = tid >> 2;          // 0..63
    int lk4 = (tid & 3) * 4;      // 0,4,8,12
    const float* Ap = A + (size_t)(m0 + lrow) * Kd + lk4;
    const float* Bp = Bw + (size_t)(n0 + lrow) * Kd + lk4;
    float rs = (MODE == 0 && rowScale != nullptr) ? rowScale[m0 + lrow] : 1.0f;
    float acc[4][4] = {};
    for (int kk = 0; kk < Kd; kk += 16) {
        float4 a = *(const float4*)(Ap + kk);
        float4 b = *(const float4*)(Bp + kk);
        __syncthreads();
        As[lk4 + 0][lrow] = a.x * rs; As[lk4 + 1][lrow] = a.y * rs;
        As[lk4 + 2][lrow] = a.z * rs; As[lk4 + 3][lrow] = a.w * rs;
        Bs[lk4 + 0][lrow] = b.x; Bs[lk4 + 1][lrow] = b.y;
        Bs[lk4 + 2][lrow] = b.z; Bs[lk4 + 3][lrow] = b.w;
        __syncthreads();
#pragma unroll
        for (int k2 = 0; k2 < 16; ++k2) {
            float4 av = *(const float4*)&As[k2][ty * 4];
            float4 bv = *(const float4*)&Bs[k2][tx * 4];
            float aa[4] = {av.x, av.y, av.z, av.w};
            float bb[4] = {bv.x, bv.y, bv.z, bv.w};
#pragma unroll
            for (int i = 0; i < 4; ++i)
#pragma unroll
                for (int j = 0; j < 4; ++j) acc[i][j] += aa[i] * bb[j];
        }
    }
#pragma unroll
    for (int i = 0; i < 4; ++i) {
        int row = m0 + ty * 4 + i;
        float* cp = C + (size_t)row * N + n0 + tx * 4;
        float4 v = make_float4(acc[i][0], acc[i][1], acc[i][2], acc[i][3]);
        if (MODE == 0) {
            *(float4*)cp = v;
        } else {
            float4 old = *(const float4*)cp;
            float4 ds = *(const float4*)(dscale + n0 + tx * 4);
            old.x += ds.x * v.x; old.y += ds.y * v.y;
            old.z += ds.z * v.z; old.w += ds.w * v.w;
            *(float4*)cp = old;
        }
    }
}

// Per (b,c) chain: normalize each 2x2 by Frobenius norm, sequential prefix
// product S = Mn @ S, emit h pair = S @ v.  4096 chains, unroll-16 prefetch.
__global__ __launch_bounds__(64) void scan_kernel(
        const float4* __restrict__ Mb4, const float* __restrict__ vv,
        float2* __restrict__ hb2) {
    int gid = blockIdx.x * 64 + threadIdx.x;   // 0..4095
    int b = gid >> 7, c = gid & 127;
    float v0 = vv[c * 2], v1 = vv[c * 2 + 1];
    float S00 = 1.f, S01 = 0.f, S10 = 0.f, S11 = 0.f;
    size_t base = (size_t)b * NT * KC + c;
    for (int t0 = 0; t0 < NT; t0 += 16) {
        float4 mm[16];
#pragma unroll
        for (int u = 0; u < 16; ++u) mm[u] = Mb4[base + (size_t)(t0 + u) * KC];
#pragma unroll
        for (int u = 0; u < 16; ++u) {
            float4 m = mm[u];
            float n2 = m.x * m.x + m.y * m.y + m.z * m.z + m.w * m.w;
            float inv = 1.0f / fmaxf(sqrtf(n2), 1e-6f);
            float a00 = m.x * inv, a01 = m.y * inv;
            float a10 = m.z * inv, a11 = m.w * inv;
            float t00 = a00 * S00 + a01 * S10;
            float t01 = a00 * S01 + a01 * S11;
            float t10 = a10 * S00 + a11 * S10;
            float t11 = a10 * S01 + a11 * S11;
            S00 = t00; S01 = t01; S10 = t10; S11 = t11;
            hb2[base + (size_t)(t0 + u) * KC] =
                make_float2(S00 * v0 + S01 * v1, S10 * v0 + S11 * v1);
        }
    }
}

// Logits tile (64 rows x 64 vocab) with softcap, reduce to per-(row,chunk)
// partial max + sumexp.  A = x * irms, B = tok_emb, K = 512.
__global__ __launch_bounds__(256) void logits_stage1_kernel(
        const float* __restrict__ x, const float* __restrict__ emb,
        const float* __restrict__ irms, float* __restrict__ pm,
        float* __restrict__ ps) {
    __shared__ float As[16][68];
    __shared__ float Bs[16][68];
    __shared__ float redm[64][17];
    __shared__ float reds[64][17];
    __shared__ float bm[64];
    int n0 = blockIdx.x * 64;    // vocab chunk * 64
    int m0 = blockIdx.y * 64;
    int tid = threadIdx.x;
    int tx = tid & 15, ty = tid >> 4;
    int lrow = tid >> 2, lk4 = (tid & 3) * 4;
    const float* Ap = x + (size_t)(m0 + lrow) * DD + lk4;
    const float* Bp = emb + (size_t)(n0 + lrow) * DD + lk4;
    float rs = irms[m0 + lrow];
    float acc[4][4] = {};
    for (int kk = 0; kk < DD; kk += 16) {
        float4 a = *(const float4*)(Ap + kk);
        float4 b = *(const float4*)(Bp + kk);
        __syncthreads();
        As[lk4 + 0][lrow] = a.x * rs; As[lk4 + 1][lrow] = a.y * rs;
        As[lk4 + 2][lrow] = a.z * rs; As[lk4 + 3][lrow] = a.w * rs;
        Bs[lk4 + 0][lrow] = b.x; Bs[lk4 + 1][lrow] = b.y;
        Bs[lk4 + 2][lrow] = b.z; Bs[lk4 + 3][lrow] = b.w;
        __syncthreads();
#pragma unroll
        for (int k2 = 0; k2 < 16; ++k2) {
            float4 av = *(const float4*)&As[k2][ty * 4];
            float4 bv = *(const float4*)&Bs[k2][tx * 4];
            float aa[4] = {av.x, av.y, av.z, av.w};
            float bb[4] = {bv.x, bv.y, bv.z, bv.w};
#pragma unroll
            for (int i = 0; i < 4; ++i)
#pragma unroll
                for (int j = 0; j < 4; ++j) acc[i][j] += aa[i] * bb[j];
        }
    }
    // softcap
    float zc[4][4];
#pragma unroll
    for (int i = 0; i < 4; ++i)
#pragma unroll
        for (int j = 0; j < 4; ++j)
            zc[i][j] = SOFTCAP * tanhf(acc[i][j] * (1.0f / SOFTCAP));
#pragma unroll
    for (int i = 0; i < 4; ++i) {
        float lm = fmaxf(fmaxf(zc[i][0], zc[i][1]), fmaxf(zc[i][2], zc[i][3]));
        redm[ty * 4 + i][tx] = lm;
    }
    __syncthreads();
    if (tid < 64) {
        float m = redm[tid][0];
#pragma unroll
        for (int c2 = 1; c2 < 16; ++c2) m = fmaxf(m, redm[tid][c2]);
        bm[tid] = m;
    }
    __syncthreads();
#pragma unroll
    for (int i = 0; i < 4; ++i) {
        float mrow = bm[ty * 4 + i];
        float s = expf(zc[i][0] - mrow) + expf(zc[i][1] - mrow) +
                  expf(zc[i][2] - mrow) + expf(zc[i][3] - mrow);
        reds[ty * 4 + i][tx] = s;
    }
    __syncthreads();
    if (tid < 64) {
        float s = 0.f;
#pragma unroll
        for (int c2 = 0; c2 < 16; ++c2) s += reds[tid][c2];
        int row = m0 + tid;
        pm[(size_t)row * NC + blockIdx.x] = bm[tid];
        ps[(size_t)row * NC + blockIdx.x] = s;
    }
}

// Combine chunk partials -> logsumexp; recompute target logit; per-row loss.
__global__ __launch_bounds__(256) void loss_stage2_kernel(
        const float* __restrict__ x, const float* __restrict__ irms,
        const float* __restrict__ emb, const int* __restrict__ tgt,
        const float* __restrict__ pm, const float* __restrict__ ps,
        float* __restrict__ rl) {
    int lane = threadIdx.x & 63, wid = threadIdx.x >> 6;
    int row = blockIdx.x * 4 + wid;
    float pmv = (lane < NC) ? pm[(size_t)row * NC + lane] : -3.0e38f;
    float m = wave_reduce_max(pmv);
    float s = (lane < NC) ? ps[(size_t)row * NC + lane] * expf(pmv - m) : 0.f;
    s = wave_reduce_sum(s);
    float lse = m + logf(s);
    int t = tgt[row];
    const float* xr = x + (size_t)row * DD;
    const float* er = emb + (size_t)t * DD;
    float z = 0.f;
#pragma unroll
    for (int d = lane; d < DD; d += 64) z += xr[d] * er[d];
    z = wave_reduce_sum(z) * irms[row];
    float zcap = SOFTCAP * tanhf(z * (1.0f / SOFTCAP));
    if (lane == 0) rl[row] = lse - zcap;
}

__global__ __launch_bounds__(1024) void finalize_kernel(
        const float* __restrict__ rl, float* __restrict__ out) {
    __shared__ float sw[16];
    float s = 0.f;
    for (int i = threadIdx.x; i < BT; i += 1024) s += rl[i];
    s = wave_reduce_sum(s);
    if ((threadIdx.x & 63) == 0) sw[threadIdx.x >> 6] = s;
    __syncthreads();
    if (threadIdx.x == 0) {
        float t = 0.f;
#pragma unroll
        for (int i = 0; i < 16; ++i) t += sw[i];
        out[0] = t * (1.0f / BT);
    }
}

extern "C" void kernel_launch(void* const* d_in, const int* in_sizes, int n_in,
                              void* d_out, int out_size, void* d_ws,
                              size_t ws_size, hipStream_t stream) {
    (void)in_sizes; (void)n_in; (void)out_size; (void)ws_size;
    const int* ids = (const int*)d_in[0];
    const int* tgt = (const int*)d_in[1];
    const float* emb = (const float*)d_in[2];
    const float* Wm = (const float*)d_in[3];   // (L, 512, 512)
    const float* vv = (const float*)d_in[4];   // (L, 128, 2, 1)
    const float* Pw = (const float*)d_in[5];   // (L, 512, 256)
    const float* osc = (const float*)d_in[6];  // (L, 512)
    float* out = (float*)d_out;
    float* ws = (float*)d_ws;

    float* x = ws;                              // BT*DD
    float* Mb = x + (size_t)BT * DD;            // BT*FF
    float* hb = Mb + (size_t)BT * FF;           // BT*HH
    float* irms = hb + (size_t)BT * HH;         // BT
    float* pm = irms + BT;                      // BT*NC
    float* ps = pm + (size_t)BT * NC;           // BT*NC
    float* rl = ps + (size_t)BT * NC;           // BT

    embed_rms_kernel<<<BT, 256, 0, stream>>>(ids, emb, x);

    for (int l = 0; l < NL; ++l) {
        rowrms_kernel<<<BT, 256, 0, stream>>>(x, irms);
        gemm_bt_kernel<0><<<dim3(FF / 64, BT / 64), 256, 0, stream>>>(
            x, Wm + (size_t)l * FF * DD, Mb, FF, DD, irms, nullptr);
        scan_kernel<<<64, 64, 0, stream>>>((const float4*)Mb, vv + l * KC * 2,
                                           (float2*)hb);
        gemm_bt_kernel<1><<<dim3(DD / 64, BT / 64), 256, 0, stream>>>(
            hb, Pw + (size_t)l * DD * HH, x, DD, HH, nullptr, osc + l * DD);
    }

    rowrms_kernel<<<BT, 256, 0, stream>>>(x, irms);
    logits_stage1_kernel<<<dim3(NV / 64, BT / 64), 256, 0, stream>>>(
        x, emb, irms, pm, ps);
    loss_stage2_kernel<<<BT / 4, 256, 0, stream>>>(x, irms, emb, tgt, pm, ps, rl);
    finalize_kernel<<<1, 1024, 0, stream>>>(rl, out);
}

// Round 2
// 1146.716 us; speedup vs baseline: 3.4065x; 3.4065x over previous
//
#include <hip/hip_runtime.h>
#include <math.h>

// Problem dims (fixed by reference setup_inputs)
constexpr int NB = 32;      // batch
constexpr int NT = 1024;    // time
constexpr int BT = 32768;   // NB*NT rows
constexpr int DD = 512;     // model dim
constexpr int KC = 128;     // k channels (2x2 matrices)
constexpr int NL = 6;       // layers
constexpr int NV = 2048;    // vocab
constexpr int HH = 256;     // k*2
constexpr int FF = 512;     // k*4
constexpr int NC = NV / 128; // vocab chunks (logits GEMM col-tiles) = 16
constexpr float EPS = 1.1920929e-07f;
constexpr float SOFTCAP = 30.0f;

typedef unsigned short u16;
typedef unsigned int u32;
using bf16x8 = __attribute__((ext_vector_type(8))) __bf16;
using f32x4 = __attribute__((ext_vector_type(4))) float;

__device__ __forceinline__ float wave_reduce_sum(float v) {
#pragma unroll
    for (int m = 32; m >= 1; m >>= 1) v += __shfl_xor(v, m, 64);
    return v;
}
__device__ __forceinline__ float wave_reduce_max(float v) {
#pragma unroll
    for (int m = 32; m >= 1; m >>= 1) v = fmaxf(v, __shfl_xor(v, m, 64));
    return v;
}

// fp32 -> bf16 round-to-nearest-even
__device__ __forceinline__ u16 f2bf(float f) {
    u32 u = __float_as_uint(f);
    u = u + 0x7FFFu + ((u >> 16) & 1u);
    return (u16)(u >> 16);
}

// async global->LDS, 16B per lane (wave-uniform LDS base + lane*16)
__device__ __forceinline__ void gload_lds16(const void* gsrc, void* ldst) {
    __builtin_amdgcn_global_load_lds(
        (const __attribute__((address_space(1))) u32*)gsrc,
        (__attribute__((address_space(3))) u32*)ldst, 16, 0, 0);
}

// ---------------------------------------------------------------- converts
__global__ __launch_bounds__(256) void conv_bf_kernel(
        const float4* __restrict__ in, u16* __restrict__ out, int n4) {
    int i = blockIdx.x * 256 + threadIdx.x;
    if (i < n4) {
        float4 v = in[i];
        uint2 p;
        p.x = (u32)f2bf(v.x) | ((u32)f2bf(v.y) << 16);
        p.y = (u32)f2bf(v.z) | ((u32)f2bf(v.w) << 16);
        *(uint2*)(out + (size_t)i * 4) = p;
    }
}

// ---------------------------------------------------------------- embed
// x[row] = rmsnorm(tok_emb[ids[row]])   (block = 256 threads, one row)
__global__ __launch_bounds__(256) void embed_rms_kernel(
        const int* __restrict__ ids, const float* __restrict__ emb,
        float* __restrict__ x) {
    __shared__ float sw[4];
    int row = blockIdx.x;
    int id = ids[row];
    const float* e = emb + (size_t)id * DD;
    float* xo = x + (size_t)row * DD;
    int t = threadIdx.x;
    float v0 = e[t], v1 = e[t + 256];
    float ss = wave_reduce_sum(v0 * v0 + v1 * v1);
    if ((t & 63) == 0) sw[t >> 6] = ss;
    __syncthreads();
    ss = sw[0] + sw[1] + sw[2] + sw[3];
    float sc = rsqrtf(ss * (1.0f / DD) + EPS);
    xo[t] = v0 * sc;
    xo[t + 256] = v1 * sc;
}

// ---------------------------------------------------------------- ynorm
// y[row] = bf16(x[row] * irms[row]); irms[row] written too. Wave per row.
__global__ __launch_bounds__(256) void ynorm_kernel(
        const float* __restrict__ x, u16* __restrict__ y,
        float* __restrict__ irms) {
    int lane = threadIdx.x & 63, wid = threadIdx.x >> 6;
    int row = blockIdx.x * 4 + wid;
    const float4* xr = (const float4*)(x + (size_t)row * DD);
    float4 a = xr[lane * 2], b = xr[lane * 2 + 1];
    float ss = a.x * a.x + a.y * a.y + a.z * a.z + a.w * a.w +
               b.x * b.x + b.y * b.y + b.z * b.z + b.w * b.w;
    ss = wave_reduce_sum(ss);
    float sc = rsqrtf(ss * (1.0f / DD) + EPS);
    u32 p0 = (u32)f2bf(a.x * sc) | ((u32)f2bf(a.y * sc) << 16);
    u32 p1 = (u32)f2bf(a.z * sc) | ((u32)f2bf(a.w * sc) << 16);
    u32 p2 = (u32)f2bf(b.x * sc) | ((u32)f2bf(b.y * sc) << 16);
    u32 p3 = (u32)f2bf(b.z * sc) | ((u32)f2bf(b.w * sc) << 16);
    *(uint4*)(y + (size_t)row * DD + lane * 8) = make_uint4(p0, p1, p2, p3);
    if (lane == 0) irms[row] = sc;
}

// ---------------------------------------------------------------- MFMA GEMM
// C[m,n] = sum_k A[m,k]*B[n,k], A:(M,K) bf16, B:(N,K) bf16 row-major.
// 128x128 tile, BK=32, 256 thr = 4 waves (2x2 of 64x64), 4x4 frags of
// mfma_f32_16x16x32_bf16 per wave per K-step. global_load_lds width-16.
// MODE 0: C(fp32) = result            (-> Mb)
// MODE 1: C[m,n] += dscale[n]*result  (residual into x)
// MODE 2: softcap + per-(row, col-chunk) max/sumexp partials -> pm, ps
template <int MODE>
__global__ __launch_bounds__(256) void gemm_mfma_kernel(
        const u16* __restrict__ A, const u16* __restrict__ B,
        float* __restrict__ C, int N, int K,
        const float* __restrict__ dscale, float* __restrict__ pm,
        float* __restrict__ ps) {
    __shared__ __align__(16) u16 As[128 * 32];
    __shared__ __align__(16) u16 Bs[128 * 32];
    int tid = threadIdx.x;
    int lane = tid & 63, wid = tid >> 6;
    int wr = wid >> 1, wc = wid & 1;
    int m0 = blockIdx.y * 128, n0 = blockIdx.x * 128;
    const u16* Ag = A + (size_t)m0 * K;
    const u16* Bg = B + (size_t)n0 * K;
    int r0 = tid >> 2;            // 0..63 staging row
    int k8 = (tid & 3) * 8;       // staging k offset (elements)
    int rl = lane & 15;           // fragment row within 16
    int kk = (lane >> 4) * 8;     // fragment k offset (elements)
    f32x4 zero4 = {0.f, 0.f, 0.f, 0.f};
    f32x4 acc[4][4];
#pragma unroll
    for (int m = 0; m < 4; ++m)
#pragma unroll
        for (int n = 0; n < 4; ++n) acc[m][n] = zero4;

    int nk = K >> 5;
    for (int kt = 0; kt < nk; ++kt) {
        int kb = (kt << 5) + k8;
        __syncthreads();
        gload_lds16(Ag + (size_t)r0 * K + kb, &As[tid * 8]);
        gload_lds16(Ag + (size_t)(r0 + 64) * K + kb, &As[(tid + 256) * 8]);
        gload_lds16(Bg + (size_t)r0 * K + kb, &Bs[tid * 8]);
        gload_lds16(Bg + (size_t)(r0 + 64) * K + kb, &Bs[(tid + 256) * 8]);
        __syncthreads();
        bf16x8 af[4], bfr[4];
#pragma unroll
        for (int m = 0; m < 4; ++m)
            af[m] = *(const bf16x8*)&As[(wr * 64 + m * 16 + rl) * 32 + kk];
#pragma unroll
        for (int n = 0; n < 4; ++n)
            bfr[n] = *(const bf16x8*)&Bs[(wc * 64 + n * 16 + rl) * 32 + kk];
#pragma unroll
        for (int m = 0; m < 4; ++m)
#pragma unroll
            for (int n = 0; n < 4; ++n)
                acc[m][n] = __builtin_amdgcn_mfma_f32_16x16x32_bf16(
                    af[m], bfr[n], acc[m][n], 0, 0, 0);
    }

    int cr = (lane >> 4) * 4;   // D-frag base row
    int cc = lane & 15;         // D-frag col
    if constexpr (MODE == 0) {
#pragma unroll
        for (int m = 0; m < 4; ++m)
#pragma unroll
            for (int n = 0; n < 4; ++n)
#pragma unroll
                for (int r = 0; r < 4; ++r) {
                    int row = m0 + wr * 64 + m * 16 + cr + r;
                    int col = n0 + wc * 64 + n * 16 + cc;
                    C[(size_t)row * N + col] = acc[m][n][r];
                }
    } else if constexpr (MODE == 1) {
        float ds[4];
#pragma unroll
        for (int n = 0; n < 4; ++n) ds[n] = dscale[n0 + wc * 64 + n * 16 + cc];
#pragma unroll
        for (int m = 0; m < 4; ++m)
#pragma unroll
            for (int n = 0; n < 4; ++n)
#pragma unroll
                for (int r = 0; r < 4; ++r) {
                    int row = m0 + wr * 64 + m * 16 + cr + r;
                    int col = n0 + wc * 64 + n * 16 + cc;
                    C[(size_t)row * N + col] += ds[n] * acc[m][n][r];
                }
    } else {
        __shared__ float redm[128][2];
        __shared__ float redsum[128][2];
#pragma unroll
        for (int m = 0; m < 4; ++m)
#pragma unroll
            for (int n = 0; n < 4; ++n)
#pragma unroll
                for (int r = 0; r < 4; ++r)
                    acc[m][n][r] =
                        SOFTCAP * tanhf(acc[m][n][r] * (1.0f / SOFTCAP));
#pragma unroll
        for (int m = 0; m < 4; ++m)
#pragma unroll
            for (int r = 0; r < 4; ++r) {
                float lm = fmaxf(fmaxf(acc[m][0][r], acc[m][1][r]),
                                 fmaxf(acc[m][2][r], acc[m][3][r]));
                lm = fmaxf(lm, __shfl_xor(lm, 1, 64));
                lm = fmaxf(lm, __shfl_xor(lm, 2, 64));
                lm = fmaxf(lm, __shfl_xor(lm, 4, 64));
                lm = fmaxf(lm, __shfl_xor(lm, 8, 64));
                if (cc == 0) redm[wr * 64 + m * 16 + cr + r][wc] = lm;
            }
        __syncthreads();
#pragma unroll
        for (int m = 0; m < 4; ++m)
#pragma unroll
            for (int r = 0; r < 4; ++r) {
                int rowb = wr * 64 + m * 16 + cr + r;
                float bm = fmaxf(redm[rowb][0], redm[rowb][1]);
                float s = expf(acc[m][0][r] - bm) + expf(acc[m][1][r] - bm) +
                          expf(acc[m][2][r] - bm) + expf(acc[m][3][r] - bm);
                s += __shfl_xor(s, 1, 64);
                s += __shfl_xor(s, 2, 64);
                s += __shfl_xor(s, 4, 64);
                s += __shfl_xor(s, 8, 64);
                if (cc == 0) redsum[rowb][wc] = s;
            }
        __syncthreads();
        if (tid < 128) {
            float bm = fmaxf(redm[tid][0], redm[tid][1]);
            pm[(size_t)(m0 + tid) * NC + blockIdx.x] = bm;
            ps[(size_t)(m0 + tid) * NC + blockIdx.x] =
                redsum[tid][0] + redsum[tid][1];
        }
    }
}

// ---------------------------------------------------------------- scan
__device__ __forceinline__ void mnorm_mul(float4 m, float& S00, float& S01,
                                          float& S10, float& S11) {
    float n2 = m.x * m.x + m.y * m.y + m.z * m.z + m.w * m.w;
    float inv = 1.0f / fmaxf(sqrtf(n2), 1e-6f);
    float a00 = m.x * inv, a01 = m.y * inv, a10 = m.z * inv, a11 = m.w * inv;
    float t00 = a00 * S00 + a01 * S10;
    float t01 = a00 * S01 + a01 * S11;
    float t10 = a10 * S00 + a11 * S10;
    float t11 = a10 * S01 + a11 * S11;
    S00 = t00; S01 = t01; S10 = t10; S11 = t11;
}

// phase 1: per (b, c, seg of 32 t): product of normalized Ms -> P
__global__ __launch_bounds__(256) void scan_seg_kernel(
        const float4* __restrict__ Mb4, float4* __restrict__ P) {
    int c = threadIdx.x & 127;
    int seg = ((blockIdx.x & 15) << 1) | (threadIdx.x >> 7);
    int b = blockIdx.x >> 4;
    size_t base = ((size_t)b * NT + seg * 32) * KC + c;
    float S00 = 1.f, S01 = 0.f, S10 = 0.f, S11 = 0.f;
#pragma unroll 4
    for (int u = 0; u < 32; ++u)
        mnorm_mul(Mb4[base + (size_t)u * KC], S00, S01, S10, S11);
    P[((size_t)b * 32 + seg) * KC + c] = make_float4(S00, S01, S10, S11);
}

// phase 2: exclusive scan of the 32 segment products per chain -> E
__global__ __launch_bounds__(256) void scan_exc_kernel(
        const float4* __restrict__ P, float4* __restrict__ E) {
    int g = blockIdx.x * 256 + threadIdx.x;  // 0..4095
    int b = g >> 7, c = g & 127;
    float S00 = 1.f, S01 = 0.f, S10 = 0.f, S11 = 0.f;
    for (int s = 0; s < 32; ++s) {
        size_t idx = ((size_t)b * 32 + s) * KC + c;
        E[idx] = make_float4(S00, S01, S10, S11);
        float4 p = P[idx];
        float t00 = p.x * S00 + p.y * S10;
        float t01 = p.x * S01 + p.y * S11;
        float t10 = p.z * S00 + p.w * S10;
        float t11 = p.z * S01 + p.w * S11;
        S00 = t00; S01 = t01; S10 = t10; S11 = t11;
    }
}

// phase 3: re-walk segment from its carry-in, emit h = S @ v as bf16 pairs
__global__ __launch_bounds__(256) void scan_apply_kernel(
        const float4* __restrict__ Mb4, const float4* __restrict__ E,
        const float* __restrict__ vv, ushort2* __restrict__ h2) {
    int c = threadIdx.x & 127;
    int seg = ((blockIdx.x & 15) << 1) | (threadIdx.x >> 7);
    int b = blockIdx.x >> 4;
    float4 e = E[((size_t)b * 32 + seg) * KC + c];
    float S00 = e.x, S01 = e.y, S10 = e.z, S11 = e.w;
    float v0 = vv[c * 2], v1 = vv[c * 2 + 1];
    size_t base = ((size_t)b * NT + seg * 32) * KC + c;
#pragma unroll 4
    for (int u = 0; u < 32; ++u) {
        mnorm_mul(Mb4[base + (size_t)u * KC], S00, S01, S10, S11);
        float h0 = S00 * v0 + S01 * v1;
        float h1 = S10 * v0 + S11 * v1;
        h2[base + (size_t)u * KC] = make_ushort2(f2bf(h0), f2bf(h1));
    }
}

// ---------------------------------------------------------------- loss
// Combine chunk partials -> logsumexp; recompute target logit fp32.
__global__ __launch_bounds__(256) void loss_stage2_kernel(
        const float* __restrict__ x, const float* __restrict__ irms,
        const float* __restrict__ emb, const int* __restrict__ tgt,
        const float* __restrict__ pm, const float* __restrict__ ps,
        float* __restrict__ rl) {
    int lane = threadIdx.x & 63, wid = threadIdx.x >> 6;
    int row = blockIdx.x * 4 + wid;
    float pmv = (lane < NC) ? pm[(size_t)row * NC + lane] : -3.0e38f;
    float m = wave_reduce_max(pmv);
    float s = (lane < NC) ? ps[(size_t)row * NC + lane] * expf(pmv - m) : 0.f;
    s = wave_reduce_sum(s);
    float lse = m + logf(s);
    int t = tgt[row];
    const float* xr = x + (size_t)row * DD;
    const float* er = emb + (size_t)t * DD;
    float z = 0.f;
#pragma unroll
    for (int d = lane; d < DD; d += 64) z += xr[d] * er[d];
    z = wave_reduce_sum(z) * irms[row];
    float zcap = SOFTCAP * tanhf(z * (1.0f / SOFTCAP));
    if (lane == 0) rl[row] = lse - zcap;
}

__global__ __launch_bounds__(1024) void finalize_kernel(
        const float* __restrict__ rl, float* __restrict__ out) {
    __shared__ float sw[16];
    float s = 0.f;
    for (int i = threadIdx.x; i < BT; i += 1024) s += rl[i];
    s = wave_reduce_sum(s);
    if ((threadIdx.x & 63) == 0) sw[threadIdx.x >> 6] = s;
    __syncthreads();
    if (threadIdx.x == 0) {
        float t = 0.f;
#pragma unroll
        for (int i = 0; i < 16; ++i) t += sw[i];
        out[0] = t * (1.0f / BT);
    }
}

// ---------------------------------------------------------------- launch
extern "C" void kernel_launch(void* const* d_in, const int* in_sizes, int n_in,
                              void* d_out, int out_size, void* d_ws,
                              size_t ws_size, hipStream_t stream) {
    (void)in_sizes; (void)n_in; (void)out_size; (void)ws_size;
    const int* ids = (const int*)d_in[0];
    const int* tgt = (const int*)d_in[1];
    const float* emb = (const float*)d_in[2];
    const float* Wm = (const float*)d_in[3];   // (L, 512, 512)
    const float* vv = (const float*)d_in[4];   // (L, 128, 2, 1)
    const float* Pw = (const float*)d_in[5];   // (L, 512, 256)
    const float* osc = (const float*)d_in[6];  // (L, 512)
    float* out = (float*)d_out;

    float* x = (float*)d_ws;                       // BT*DD f32      64MB
    u16* y = (u16*)(x + (size_t)BT * DD);          // BT*DD bf16     32MB
    float* Mb = (float*)(y + (size_t)BT * DD);     // BT*FF f32      64MB
    u16* hbf = (u16*)(Mb + (size_t)BT * FF);       // BT*HH bf16     16MB
    float* P = (float*)(hbf + (size_t)BT * HH);    // 4096*32*4 f32   2MB
    float* E = P + (size_t)4096 * 32 * 4;          //                 2MB
    float* irms = E + (size_t)4096 * 32 * 4;       // BT
    float* pm = irms + BT;                         // BT*NC           2MB
    float* ps = pm + (size_t)BT * NC;              // BT*NC           2MB
    float* rl = ps + (size_t)BT * NC;              // BT
    u16* WmBf = (u16*)(rl + BT);                   // 6*512*512 bf16
    u16* PwBf = WmBf + (size_t)NL * FF * DD;       // 6*512*256 bf16
    u16* embBf = PwBf + (size_t)NL * DD * HH;      // 2048*512 bf16

    conv_bf_kernel<<<1536, 256, 0, stream>>>((const float4*)Wm, WmBf,
                                             NL * FF * DD / 4);
    conv_bf_kernel<<<768, 256, 0, stream>>>((const float4*)Pw, PwBf,
                                            NL * DD * HH / 4);
    conv_bf_kernel<<<1024, 256, 0, stream>>>((const float4*)emb, embBf,
                                             NV * DD / 4);
    embed_rms_kernel<<<BT, 256, 0, stream>>>(ids, emb, x);

    for (int l = 0; l < NL; ++l) {
        ynorm_kernel<<<BT / 4, 256, 0, stream>>>(x, y, irms);
        gemm_mfma_kernel<0><<<dim3(FF / 128, BT / 128), 256, 0, stream>>>(
            y, WmBf + (size_t)l * FF * DD, Mb, FF, DD, nullptr, nullptr,
            nullptr);
        scan_seg_kernel<<<512, 256, 0, stream>>>((const float4*)Mb,
                                                 (float4*)P);
        scan_exc_kernel<<<16, 256, 0, stream>>>((const float4*)P, (float4*)E);
        scan_apply_kernel<<<512, 256, 0, stream>>>(
            (const float4*)Mb, (const float4*)E, vv + l * HH, (ushort2*)hbf);
        gemm_mfma_kernel<1><<<dim3(DD / 128, BT / 128), 256, 0, stream>>>(
            hbf, PwBf + (size_t)l * DD * HH, x, DD, HH, osc + (size_t)l * DD,
            nullptr, nullptr);
    }

    ynorm_kernel<<<BT / 4, 256, 0, stream>>>(x, y, irms);
    gemm_mfma_kernel<2><<<dim3(NV / 128, BT / 128), 256, 0, stream>>>(
        y, embBf, nullptr, NV, DD, nullptr, pm, ps);
    loss_stage2_kernel<<<BT / 4, 256, 0, stream>>>(x, irms, emb, tgt, pm, ps,
                                                   rl);
    finalize_kernel<<<1, 1024, 0, stream>>>(rl, out);
}

// Round 4
// 1048.210 us; speedup vs baseline: 3.7266x; 1.0940x over previous
//
#include <hip/hip_runtime.h>
#include <math.h>

// Problem dims (fixed by reference setup_inputs)
constexpr int NB = 32;      // batch
constexpr int NT = 1024;    // time
constexpr int BT = 32768;   // NB*NT rows
constexpr int DD = 512;     // model dim
constexpr int KC = 128;     // k channels (2x2 matrices)
constexpr int NL = 6;       // layers
constexpr int NV = 2048;    // vocab
constexpr int HH = 256;     // k*2
constexpr int FF = 512;     // k*4
constexpr int NC = NV / 128; // vocab chunks (logits GEMM col-tiles) = 16
constexpr float EPS = 1.1920929e-07f;
constexpr float SOFTCAP = 30.0f;

typedef unsigned short u16;
typedef unsigned int u32;
using bf16x8 = __attribute__((ext_vector_type(8))) __bf16;
using f32x4 = __attribute__((ext_vector_type(4))) float;

__device__ __forceinline__ float wave_reduce_sum(float v) {
#pragma unroll
    for (int m = 32; m >= 1; m >>= 1) v += __shfl_xor(v, m, 64);
    return v;
}
__device__ __forceinline__ float wave_reduce_max(float v) {
#pragma unroll
    for (int m = 32; m >= 1; m >>= 1) v = fmaxf(v, __shfl_xor(v, m, 64));
    return v;
}

// fp32 -> bf16 round-to-nearest-even
__device__ __forceinline__ u16 f2bf(float f) {
    u32 u = __float_as_uint(f);
    u = u + 0x7FFFu + ((u >> 16) & 1u);
    return (u16)(u >> 16);
}
__device__ __forceinline__ float bf2f(u16 v) {
    return __uint_as_float((u32)v << 16);
}

// exact-enough softcap: 30*tanh(z/30), tanh via fast exp (correct at +-inf)
__device__ __forceinline__ float softcap30(float z) {
    float e = __expf(z * (2.0f / SOFTCAP));
    return SOFTCAP * (1.0f - 2.0f / (e + 1.0f));
}

// async global->LDS, 16B per lane (wave-uniform LDS base + lane*16)
__device__ __forceinline__ void gload_lds16(const void* gsrc, void* ldst) {
    __builtin_amdgcn_global_load_lds(
        (const __attribute__((address_space(1))) u32*)gsrc,
        (__attribute__((address_space(3))) u32*)ldst, 16, 0, 0);
}

// bijective XCD-chunk swizzle: hardware bid round-robins 8 XCDs; give each
// XCD a contiguous tile range so row-stripes stay in its private L2.
__device__ __forceinline__ int2 swz_tile(int nbx, int nwg) {
    int bid = blockIdx.x;
    int cpx = nwg >> 3;   // nwg % 8 == 0 for all our grids
    int swz = (bid & 7) * cpx + (bid >> 3);
    return make_int2(swz % nbx, swz / nbx);
}

// ---------------------------------------------------------------- converts
__global__ __launch_bounds__(256) void conv_bf_kernel(
        const float4* __restrict__ in, u16* __restrict__ out, int n4) {
    int i = blockIdx.x * 256 + threadIdx.x;
    if (i < n4) {
        float4 v = in[i];
        uint2 p;
        p.x = (u32)f2bf(v.x) | ((u32)f2bf(v.y) << 16);
        p.y = (u32)f2bf(v.z) | ((u32)f2bf(v.w) << 16);
        *(uint2*)(out + (size_t)i * 4) = p;
    }
}

// ---------------------------------------------------------------- embed
__global__ __launch_bounds__(256) void embed_rms_kernel(
        const int* __restrict__ ids, const float* __restrict__ emb,
        float* __restrict__ x) {
    __shared__ float sw[4];
    int row = blockIdx.x;
    int id = ids[row];
    const float* e = emb + (size_t)id * DD;
    float* xo = x + (size_t)row * DD;
    int t = threadIdx.x;
    float v0 = e[t], v1 = e[t + 256];
    float ss = wave_reduce_sum(v0 * v0 + v1 * v1);
    if ((t & 63) == 0) sw[t >> 6] = ss;
    __syncthreads();
    ss = sw[0] + sw[1] + sw[2] + sw[3];
    float sc = rsqrtf(ss * (1.0f / DD) + EPS);
    xo[t] = v0 * sc;
    xo[t + 256] = v1 * sc;
}

// ---------------------------------------------------------------- ynorm
// y[row] = bf16(x[row] * irms[row]); irms[row] written too. Wave per row.
__global__ __launch_bounds__(256) void ynorm_kernel(
        const float* __restrict__ x, u16* __restrict__ y,
        float* __restrict__ irms) {
    int lane = threadIdx.x & 63, wid = threadIdx.x >> 6;
    int row = blockIdx.x * 4 + wid;
    const float4* xr = (const float4*)(x + (size_t)row * DD);
    float4 a = xr[lane * 2], b = xr[lane * 2 + 1];
    float ss = a.x * a.x + a.y * a.y + a.z * a.z + a.w * a.w +
               b.x * b.x + b.y * b.y + b.z * b.z + b.w * b.w;
    ss = wave_reduce_sum(ss);
    float sc = rsqrtf(ss * (1.0f / DD) + EPS);
    u32 p0 = (u32)f2bf(a.x * sc) | ((u32)f2bf(a.y * sc) << 16);
    u32 p1 = (u32)f2bf(a.z * sc) | ((u32)f2bf(a.w * sc) << 16);
    u32 p2 = (u32)f2bf(b.x * sc) | ((u32)f2bf(b.y * sc) << 16);
    u32 p3 = (u32)f2bf(b.z * sc) | ((u32)f2bf(b.w * sc) << 16);
    *(uint4*)(y + (size_t)row * DD + lane * 8) = make_uint4(p0, p1, p2, p3);
    if (lane == 0) irms[row] = sc;
}

// ---------------------------------------------------------------- MFMA GEMM
// C[m,n] = sum_k A[m,k]*B[n,k], A:(M,K) bf16, B:(N,K) bf16 row-major.
// 128x128 tile, BK=32, 256 thr = 4 waves (2x2 of 64x64), 4x4 frags of
// mfma_f32_16x16x32_bf16. 1D grid + XCD-chunk swizzle.
// MODE 0: Cb(bf16) = result            (-> Mb bf16)
// MODE 1: C[m,n] += dscale[n]*result   (residual into x, fp32)
// MODE 2: softcap + per-(row, col-chunk) max/sumexp partials -> pm, ps
template <int MODE>
__global__ __launch_bounds__(256) void gemm_mfma_kernel(
        const u16* __restrict__ A, const u16* __restrict__ B,
        float* __restrict__ C, u16* __restrict__ Cb, int nbx, int nwg, int N,
        int K, const float* __restrict__ dscale, float* __restrict__ pm,
        float* __restrict__ ps) {
    __shared__ __align__(16) u16 As[128 * 32];
    __shared__ __align__(16) u16 Bs[128 * 32];
    int2 tc = swz_tile(nbx, nwg);
    int tx = tc.x, ty = tc.y;
    int tid = threadIdx.x;
    int lane = tid & 63, wid = tid >> 6;
    int wr = wid >> 1, wc = wid & 1;
    int m0 = ty * 128, n0 = tx * 128;
    const u16* Ag = A + (size_t)m0 * K;
    const u16* Bg = B + (size_t)n0 * K;
    int r0 = tid >> 2;            // 0..63 staging row
    int k8 = (tid & 3) * 8;       // staging k offset (elements)
    int rl = lane & 15;           // fragment row within 16
    int kk = (lane >> 4) * 8;     // fragment k offset (elements)
    f32x4 zero4 = {0.f, 0.f, 0.f, 0.f};
    f32x4 acc[4][4];
#pragma unroll
    for (int m = 0; m < 4; ++m)
#pragma unroll
        for (int n = 0; n < 4; ++n) acc[m][n] = zero4;

    int nk = K >> 5;
    for (int kt = 0; kt < nk; ++kt) {
        int kb = (kt << 5) + k8;
        __syncthreads();
        gload_lds16(Ag + (size_t)r0 * K + kb, &As[tid * 8]);
        gload_lds16(Ag + (size_t)(r0 + 64) * K + kb, &As[(tid + 256) * 8]);
        gload_lds16(Bg + (size_t)r0 * K + kb, &Bs[tid * 8]);
        gload_lds16(Bg + (size_t)(r0 + 64) * K + kb, &Bs[(tid + 256) * 8]);
        __syncthreads();
        bf16x8 af[4], bfr[4];
#pragma unroll
        for (int m = 0; m < 4; ++m)
            af[m] = *(const bf16x8*)&As[(wr * 64 + m * 16 + rl) * 32 + kk];
#pragma unroll
        for (int n = 0; n < 4; ++n)
            bfr[n] = *(const bf16x8*)&Bs[(wc * 64 + n * 16 + rl) * 32 + kk];
#pragma unroll
        for (int m = 0; m < 4; ++m)
#pragma unroll
            for (int n = 0; n < 4; ++n)
                acc[m][n] = __builtin_amdgcn_mfma_f32_16x16x32_bf16(
                    af[m], bfr[n], acc[m][n], 0, 0, 0);
    }

    int cr = (lane >> 4) * 4;   // D-frag base row
    int cc = lane & 15;         // D-frag col
    if constexpr (MODE == 0) {
#pragma unroll
        for (int m = 0; m < 4; ++m)
#pragma unroll
            for (int n = 0; n < 4; ++n)
#pragma unroll
                for (int r = 0; r < 4; ++r) {
                    int row = m0 + wr * 64 + m * 16 + cr + r;
                    int col = n0 + wc * 64 + n * 16 + cc;
                    Cb[(size_t)row * N + col] = f2bf(acc[m][n][r]);
                }
    } else if constexpr (MODE == 1) {
        float ds[4];
#pragma unroll
        for (int n = 0; n < 4; ++n) ds[n] = dscale[n0 + wc * 64 + n * 16 + cc];
#pragma unroll
        for (int m = 0; m < 4; ++m)
#pragma unroll
            for (int n = 0; n < 4; ++n)
#pragma unroll
                for (int r = 0; r < 4; ++r) {
                    int row = m0 + wr * 64 + m * 16 + cr + r;
                    int col = n0 + wc * 64 + n * 16 + cc;
                    C[(size_t)row * N + col] += ds[n] * acc[m][n][r];
                }
    } else {
        __shared__ float redm[128][2];
        __shared__ float redsum[128][2];
#pragma unroll
        for (int m = 0; m < 4; ++m)
#pragma unroll
            for (int n = 0; n < 4; ++n)
#pragma unroll
                for (int r = 0; r < 4; ++r)
                    acc[m][n][r] = softcap30(acc[m][n][r]);
#pragma unroll
        for (int m = 0; m < 4; ++m)
#pragma unroll
            for (int r = 0; r < 4; ++r) {
                float lm = fmaxf(fmaxf(acc[m][0][r], acc[m][1][r]),
                                 fmaxf(acc[m][2][r], acc[m][3][r]));
                lm = fmaxf(lm, __shfl_xor(lm, 1, 64));
                lm = fmaxf(lm, __shfl_xor(lm, 2, 64));
                lm = fmaxf(lm, __shfl_xor(lm, 4, 64));
                lm = fmaxf(lm, __shfl_xor(lm, 8, 64));
                if (cc == 0) redm[wr * 64 + m * 16 + cr + r][wc] = lm;
            }
        __syncthreads();
#pragma unroll
        for (int m = 0; m < 4; ++m)
#pragma unroll
            for (int r = 0; r < 4; ++r) {
                int rowb = wr * 64 + m * 16 + cr + r;
                float bm = fmaxf(redm[rowb][0], redm[rowb][1]);
                float s = __expf(acc[m][0][r] - bm) + __expf(acc[m][1][r] - bm) +
                          __expf(acc[m][2][r] - bm) + __expf(acc[m][3][r] - bm);
                s += __shfl_xor(s, 1, 64);
                s += __shfl_xor(s, 2, 64);
                s += __shfl_xor(s, 4, 64);
                s += __shfl_xor(s, 8, 64);
                if (cc == 0) redsum[rowb][wc] = s;
            }
        __syncthreads();
        if (tid < 128) {
            float bm = fmaxf(redm[tid][0], redm[tid][1]);
            pm[(size_t)(m0 + tid) * NC + tx] = bm;
            ps[(size_t)(m0 + tid) * NC + tx] = redsum[tid][0] + redsum[tid][1];
        }
    }
}

// ---------------------------------------------------------------- scan
// step: unpack bf16 2x2, Frobenius-normalize in fp32, S = Mn @ S
__device__ __forceinline__ void mstep(ushort4 mv, float& S00, float& S01,
                                      float& S10, float& S11) {
    float e0 = bf2f(mv.x), e1 = bf2f(mv.y), e2 = bf2f(mv.z), e3 = bf2f(mv.w);
    float n2 = e0 * e0 + e1 * e1 + e2 * e2 + e3 * e3;
    float inv = 1.0f / fmaxf(sqrtf(n2), 1e-6f);
    float a00 = e0 * inv, a01 = e1 * inv, a10 = e2 * inv, a11 = e3 * inv;
    float t00 = a00 * S00 + a01 * S10;
    float t01 = a00 * S01 + a01 * S11;
    float t10 = a10 * S00 + a11 * S10;
    float t11 = a10 * S01 + a11 * S11;
    S00 = t00; S01 = t01; S10 = t10; S11 = t11;
}

// phase 1: per (b, c, seg of 32 t): product of normalized Ms -> P
__global__ __launch_bounds__(256) void scan_seg_kernel(
        const ushort4* __restrict__ Mh, float4* __restrict__ P) {
    int c = threadIdx.x & 127;
    int seg = ((blockIdx.x & 15) << 1) | (threadIdx.x >> 7);
    int b = blockIdx.x >> 4;
    size_t base = ((size_t)b * NT + seg * 32) * KC + c;
    float S00 = 1.f, S01 = 0.f, S10 = 0.f, S11 = 0.f;
#pragma unroll 4
    for (int u = 0; u < 32; ++u)
        mstep(Mh[base + (size_t)u * KC], S00, S01, S10, S11);
    P[((size_t)b * 32 + seg) * KC + c] = make_float4(S00, S01, S10, S11);
}

// phase 2: exclusive scan of the 32 segment products per chain -> E
__global__ __launch_bounds__(256) void scan_exc_kernel(
        const float4* __restrict__ P, float4* __restrict__ E) {
    int g = blockIdx.x * 256 + threadIdx.x;  // 0..4095
    int b = g >> 7, c = g & 127;
    float S00 = 1.f, S01 = 0.f, S10 = 0.f, S11 = 0.f;
    for (int s = 0; s < 32; ++s) {
        size_t idx = ((size_t)b * 32 + s) * KC + c;
        E[idx] = make_float4(S00, S01, S10, S11);
        float4 p = P[idx];
        float t00 = p.x * S00 + p.y * S10;
        float t01 = p.x * S01 + p.y * S11;
        float t10 = p.z * S00 + p.w * S10;
        float t11 = p.z * S01 + p.w * S11;
        S00 = t00; S01 = t01; S10 = t10; S11 = t11;
    }
}

// phase 3: re-walk segment from its carry-in, emit h = S @ v as bf16 pairs
__global__ __launch_bounds__(256) void scan_apply_kernel(
        const ushort4* __restrict__ Mh, const float4* __restrict__ E,
        const float* __restrict__ vv, ushort2* __restrict__ h2) {
    int c = threadIdx.x & 127;
    int seg = ((blockIdx.x & 15) << 1) | (threadIdx.x >> 7);
    int b = blockIdx.x >> 4;
    float4 e = E[((size_t)b * 32 + seg) * KC + c];
    float S00 = e.x, S01 = e.y, S10 = e.z, S11 = e.w;
    float v0 = vv[c * 2], v1 = vv[c * 2 + 1];
    size_t base = ((size_t)b * NT + seg * 32) * KC + c;
#pragma unroll 4
    for (int u = 0; u < 32; ++u) {
        mstep(Mh[base + (size_t)u * KC], S00, S01, S10, S11);
        float h0 = S00 * v0 + S01 * v1;
        float h1 = S10 * v0 + S11 * v1;
        h2[base + (size_t)u * KC] = make_ushort2(f2bf(h0), f2bf(h1));
    }
}

// ---------------------------------------------------------------- loss
__global__ __launch_bounds__(256) void loss_stage2_kernel(
        const float* __restrict__ x, const float* __restrict__ irms,
        const float* __restrict__ emb, const int* __restrict__ tgt,
        const float* __restrict__ pm, const float* __restrict__ ps,
        float* __restrict__ rl) {
    int lane = threadIdx.x & 63, wid = threadIdx.x >> 6;
    int row = blockIdx.x * 4 + wid;
    float pmv = (lane < NC) ? pm[(size_t)row * NC + lane] : -3.0e38f;
    float m = wave_reduce_max(pmv);
    float s = (lane < NC) ? ps[(size_t)row * NC + lane] * __expf(pmv - m) : 0.f;
    s = wave_reduce_sum(s);
    float lse = m + __logf(s);
    int t = tgt[row];
    const float* xr = x + (size_t)row * DD;
    const float* er = emb + (size_t)t * DD;
    float z = 0.f;
#pragma unroll
    for (int d = lane; d < DD; d += 64) z += xr[d] * er[d];
    z = wave_reduce_sum(z) * irms[row];
    if (lane == 0) rl[row] = lse - softcap30(z);
}

__global__ __launch_bounds__(1024) void finalize_kernel(
        const float* __restrict__ rl, float* __restrict__ out) {
    __shared__ float sw[16];
    float s = 0.f;
    for (int i = threadIdx.x; i < BT; i += 1024) s += rl[i];
    s = wave_reduce_sum(s);
    if ((threadIdx.x & 63) == 0) sw[threadIdx.x >> 6] = s;
    __syncthreads();
    if (threadIdx.x == 0) {
        float t = 0.f;
#pragma unroll
        for (int i = 0; i < 16; ++i) t += sw[i];
        out[0] = t * (1.0f / BT);
    }
}

// ---------------------------------------------------------------- launch
extern "C" void kernel_launch(void* const* d_in, const int* in_sizes, int n_in,
                              void* d_out, int out_size, void* d_ws,
                              size_t ws_size, hipStream_t stream) {
    (void)in_sizes; (void)n_in; (void)out_size; (void)ws_size;
    const int* ids = (const int*)d_in[0];
    const int* tgt = (const int*)d_in[1];
    const float* emb = (const float*)d_in[2];
    const float* Wm = (const float*)d_in[3];   // (L, 512, 512)
    const float* vv = (const float*)d_in[4];   // (L, 128, 2, 1)
    const float* Pw = (const float*)d_in[5];   // (L, 512, 256)
    const float* osc = (const float*)d_in[6];  // (L, 512)
    float* out = (float*)d_out;

    float* x = (float*)d_ws;                       // BT*DD f32      64MB
    u16* y = (u16*)(x + (size_t)BT * DD);          // BT*DD bf16     32MB
    u16* Mbh = y + (size_t)BT * DD;                // BT*FF bf16     32MB
    u16* hbf = Mbh + (size_t)BT * FF;              // BT*HH bf16     16MB
    float* P = (float*)(hbf + (size_t)BT * HH);    // 4096*32*4 f32   2MB
    float* E = P + (size_t)4096 * 32 * 4;          //                 2MB
    float* irms = E + (size_t)4096 * 32 * 4;       // BT
    float* pm = irms + BT;                         // BT*NC           2MB
    float* ps = pm + (size_t)BT * NC;              // BT*NC           2MB
    float* rl = ps + (size_t)BT * NC;              // BT
    u16* WmBf = (u16*)(rl + BT);                   // 6*512*512 bf16
    u16* PwBf = WmBf + (size_t)NL * FF * DD;       // 6*512*256 bf16
    u16* embBf = PwBf + (size_t)NL * DD * HH;      // 2048*512 bf16

    conv_bf_kernel<<<1536, 256, 0, stream>>>((const float4*)Wm, WmBf,
                                             NL * FF * DD / 4);
    conv_bf_kernel<<<768, 256, 0, stream>>>((const float4*)Pw, PwBf,
                                            NL * DD * HH / 4);
    conv_bf_kernel<<<1024, 256, 0, stream>>>((const float4*)emb, embBf,
                                             NV * DD / 4);
    embed_rms_kernel<<<BT, 256, 0, stream>>>(ids, emb, x);

    for (int l = 0; l < NL; ++l) {
        ynorm_kernel<<<BT / 4, 256, 0, stream>>>(x, y, irms);
        gemm_mfma_kernel<0><<<(FF / 128) * (BT / 128), 256, 0, stream>>>(
            y, WmBf + (size_t)l * FF * DD, nullptr, Mbh, FF / 128,
            (FF / 128) * (BT / 128), FF, DD, nullptr, nullptr, nullptr);
        scan_seg_kernel<<<512, 256, 0, stream>>>((const ushort4*)Mbh,
                                                 (float4*)P);
        scan_exc_kernel<<<16, 256, 0, stream>>>((const float4*)P, (float4*)E);
        scan_apply_kernel<<<512, 256, 0, stream>>>(
            (const ushort4*)Mbh, (const float4*)E, vv + l * HH, (ushort2*)hbf);
        gemm_mfma_kernel<1><<<(DD / 128) * (BT / 128), 256, 0, stream>>>(
            hbf, PwBf + (size_t)l * DD * HH, x, nullptr, DD / 128,
            (DD / 128) * (BT / 128), DD, HH, osc + (size_t)l * DD, nullptr,
            nullptr);
    }

    ynorm_kernel<<<BT / 4, 256, 0, stream>>>(x, y, irms);
    gemm_mfma_kernel<2><<<(NV / 128) * (BT / 128), 256, 0, stream>>>(
        y, embBf, nullptr, nullptr, NV / 128, (NV / 128) * (BT / 128), NV, DD,
        nullptr, pm, ps);
    loss_stage2_kernel<<<BT / 4, 256, 0, stream>>>(x, irms, emb, tgt, pm, ps,
                                                   rl);
    finalize_kernel<<<1, 1024, 0, stream>>>(rl, out);
}